// Round 4
// baseline (591.703 us; speedup 1.0000x reference)
//
#include <hip/hip_runtime.h>
#include <hip/hip_bf16.h>

#define BB 256
#define LL 200
#define CC 4
#define HH 128
#define G3 384

typedef short bf16x8 __attribute__((ext_vector_type(8)));
typedef float f32x4 __attribute__((ext_vector_type(4)));

#define MFMA16(a, b, c) __builtin_amdgcn_mfma_f32_16x16x32_bf16((a), (b), (c), 0, 0, 0)

__device__ __forceinline__ short bf16_rne(float x) {
    union { float f; unsigned u; } v; v.f = x;
    unsigned r = v.u + 0x7FFFu + ((v.u >> 16) & 1u);
    return (short)(r >> 16);
}
__device__ __forceinline__ float bf16_tof(short b) {
    union { unsigned u; float f; } v; v.u = ((unsigned)(unsigned short)b) << 16;
    return v.f;
}
__device__ __forceinline__ float rcp_(float x) { return __builtin_amdgcn_rcpf(x); }
__device__ __forceinline__ float sigm_(float x) { return rcp_(1.0f + __expf(-x)); }
__device__ __forceinline__ float tanhf_(float x) { return 2.0f * rcp_(1.0f + __expf(-2.0f * x)) - 1.0f; }

// ---------------------------------------------------------------------------
// lengths from timeline_mask (bool-dtype detection, verified R1-R3)
// ---------------------------------------------------------------------------
__global__ void compute_lens_kernel(const unsigned char* __restrict__ mask8,
                                    int* __restrict__ lens) {
    __shared__ int bad;
    int b = threadIdx.x;
    if (b == 0) bad = 0;
    __syncthreads();
    int cnt8 = 0, prev = 0, mono = 1;
    for (int t = 0; t < LL; ++t) {
        int v = mask8[b * LL + t] ? 1 : 0;
        cnt8 += (v == 0);
        if (v < prev) mono = 0;
        prev = v;
    }
    if (!mono) atomicAdd(&bad, 1);
    __syncthreads();
    int len;
    if (bad == 0) {
        len = cnt8;
    } else {
        const int* m32 = (const int*)mask8;
        int c = 0;
        for (int t = 0; t < LL; ++t) c += (m32[b * LL + t] == 0);
        len = c;
    }
    if (len < 1) len = 1;
    if (len > LL) len = LL;
    lens[b] = len;
}

// ---------------------------------------------------------------------------
// weight split: whh -> hi+lo residual, wih -> hi only
// ---------------------------------------------------------------------------
__global__ void wsplit_kernel(const float* __restrict__ Wih, const float* __restrict__ Whh,
                              short* __restrict__ wih_hi,
                              short* __restrict__ whh_hi, short* __restrict__ whh_lo) {
    int i = blockIdx.x * 256 + threadIdx.x;   // grid 768 -> 196608 = 4*384*128
    float a = Wih[i];
    wih_hi[i] = bf16_rne(a);
    float b = Whh[i];
    short hb = bf16_rne(b);
    whh_hi[i] = hb; whh_lo[i] = bf16_rne(b - bf16_tof(hb));
}

// ---------------------------------------------------------------------------
// Fully fused GRU: 128 WGs (32 b-tiles x 4 c), 256 thr (4 waves), M=8.
//  - W_hh hi/lo fragments pinned in registers (3-term split, R3-proven).
//  - W_ih hi fragments in LDS (wave-private, 24 ds_read_b128/step off crit path).
//  - x projection for step s+1 computed DURING step s (independent work that
//    fills the recurrence's latency); xacc stays in registers start-to-finish.
//  - h double-buffered in LDS in A-fragment layout; one raw barrier/step with
//    lgkm-only drain (x loads and out stores stay in flight across it).
// ---------------------------------------------------------------------------
__global__ __launch_bounds__(256, 1) void gru_fused_kernel(
    const float* __restrict__ seqs,    // (B,L,C,H)
    const int*   __restrict__ lens,    // (B,)
    const short* __restrict__ wih_hi,  // (C,384,128) bf16
    const short* __restrict__ whh_hi,  // (C,384,128) bf16
    const short* __restrict__ whh_lo,
    const float* __restrict__ b_ih,    // (C,384)
    const float* __restrict__ b_hh,    // (C,384)
    float*       __restrict__ out)     // (C,B,L,H)
{
    const int bt = blockIdx.x;             // 0..31 (8 b each)
    const int c  = blockIdx.y;             // 0..3
    const int bbase = bt * 8;
    const int tid = threadIdx.x;
    const int l = tid & 63, w = tid >> 6;
    const int l15 = l & 15, l4 = l >> 4;

    __shared__ __align__(16) short wfrag[24][4][512];      // 96 KB  W_ih-hi B-frags
    __shared__ __align__(16) short hfrag[2][2][4][512];    // 16 KB  h hi/lo A-frags

    // ---- stage W_ih fragments (each wave stages exactly its own 6 NT) ----
    #pragma unroll
    for (int q = 0; q < 6; ++q) {
        int NT = (q < 2) ? (2 * w + q) : (q < 4) ? (8 + 2 * w + (q - 2)) : (16 + 2 * w + (q - 4));
        #pragma unroll
        for (int ks = 0; ks < 4; ++ks) {
            bf16x8 v = *(const bf16x8*)(wih_hi + (size_t)(c * G3 + NT * 16 + l15) * HH + ks * 32 + l4 * 8);
            *(bf16x8*)&wfrag[NT][ks][l * 8] = v;
        }
    }

    // ---- pin W_hh hi/lo fragments in registers ----
    float4 Bh4[6][4], Bl4[6][4];
    #pragma unroll
    for (int q = 0; q < 6; ++q) {
        int NT = (q < 2) ? (2 * w + q) : (q < 4) ? (8 + 2 * w + (q - 2)) : (16 + 2 * w + (q - 4));
        #pragma unroll
        for (int ks = 0; ks < 4; ++ks) {
            size_t wi = (size_t)(c * G3 + NT * 16 + l15) * HH + ks * 32 + l4 * 8;
            Bh4[q][ks] = *(const float4*)(whh_hi + wi);
            Bl4[q][ks] = *(const float4*)(whh_lo + wi);
            asm volatile("" : "+v"(Bh4[q][ks].x), "+v"(Bh4[q][ks].y), "+v"(Bh4[q][ks].z), "+v"(Bh4[q][ks].w));
            asm volatile("" : "+v"(Bl4[q][ks].x), "+v"(Bl4[q][ks].y), "+v"(Bl4[q][ks].z), "+v"(Bl4[q][ks].w));
        }
    }

    // ---- zero hfrag[0] ----
    for (int i = tid; i < 2048; i += 256) ((int*)hfrag)[i] = 0;

    // ---- biases (R/Z folded; N kept split x-side/h-side) ----
    float bR[2], bZ[2], bIN[2], bHN[2];
    #pragma unroll
    for (int cp = 0; cp < 2; ++cp) {
        int col = 32 * w + cp * 16 + l15;
        bR[cp]  = b_hh[c * G3 + col]       + b_ih[c * G3 + col];
        bZ[cp]  = b_hh[c * G3 + 128 + col] + b_ih[c * G3 + 128 + col];
        bHN[cp] = b_hh[c * G3 + 256 + col];
        bIN[cp] = b_ih[c * G3 + 256 + col];
    }

    // ---- per-lane counters ----
    const int bx = bbase + (l15 & 7);          // x-row owner
    const int lenx = lens[bx];
    int txc = LL - lenx;                       // t of next x load (s=0)
    const float* xbase = seqs + ((size_t)bx * LL * CC + c) * HH + l4 * 8;

    int lenr[4], tcur[4];
    #pragma unroll
    for (int r = 0; r < 4; ++r) {
        int b = bbase + (l4 & 1) * 4 + r;
        lenr[r] = lens[b];
        tcur[r] = LL - lenr[r];
    }
    const size_t outrow = (size_t)LL * HH;
    float* outb0 = out + ((size_t)(c * BB + bbase + (l4 & 1) * 4) * LL) * HH + 32 * w + l15;

    float hold[2][4];
    #pragma unroll
    for (int cp = 0; cp < 2; ++cp)
        #pragma unroll
        for (int r = 0; r < 4; ++r) hold[cp][r] = 0.f;

    // ---- issue x(0) loads ----
    float4 xr0[4], xr1[4];
    {
        const float* p = xbase + (size_t)txc * (CC * HH);
        #pragma unroll
        for (int ks = 0; ks < 4; ++ks) { xr0[ks] = *(const float4*)(p + ks * 32); xr1[ks] = *(const float4*)(p + ks * 32 + 4); }
        txc = (txc + 1 == LL) ? 0 : txc + 1;
    }

    __syncthreads();   // wfrag + hfrag[0] ready

    // ---- prologue: convert x(0), issue x(1), xproj -> xacc ----
    f32x4 xacc[6];
    bf16x8 xh[4], xl[4];
    #pragma unroll
    for (int ks = 0; ks < 4; ++ks) {
        float f[8] = { xr0[ks].x, xr0[ks].y, xr0[ks].z, xr0[ks].w, xr1[ks].x, xr1[ks].y, xr1[ks].z, xr1[ks].w };
        bf16x8 vh, vl;
        #pragma unroll
        for (int j = 0; j < 8; ++j) {
            short hi = bf16_rne(f[j]);
            vh[j] = hi; vl[j] = bf16_rne(f[j] - bf16_tof(hi));
        }
        xh[ks] = vh; xl[ks] = vl;
    }
    {
        const float* p = xbase + (size_t)txc * (CC * HH);
        #pragma unroll
        for (int ks = 0; ks < 4; ++ks) { xr0[ks] = *(const float4*)(p + ks * 32); xr1[ks] = *(const float4*)(p + ks * 32 + 4); }
        txc = (txc + 1 == LL) ? 0 : txc + 1;
    }
    #pragma unroll
    for (int q = 0; q < 6; ++q) { xacc[q][0] = 0.f; xacc[q][1] = 0.f; xacc[q][2] = 0.f; xacc[q][3] = 0.f; }
    #pragma unroll
    for (int ks = 0; ks < 4; ++ks) {
        #pragma unroll
        for (int q = 0; q < 6; ++q) {
            int NT = (q < 2) ? (2 * w + q) : (q < 4) ? (8 + 2 * w + (q - 2)) : (16 + 2 * w + (q - 4));
            bf16x8 wv = *(const bf16x8*)&wfrag[NT][ks][l * 8];
            xacc[q] = MFMA16(xh[ks], wv, xacc[q]);
            xacc[q] = MFMA16(xl[ks], wv, xacc[q]);
        }
    }

    // =======================  main loop  =======================
    for (int si = 0; si < LL; ++si) {
        const int cur = si & 1, nxt = cur ^ 1;

        // 1. h A-fragments
        bf16x8 ah[4], al[4];
        #pragma unroll
        for (int ks = 0; ks < 4; ++ks) {
            ah[ks] = *(const bf16x8*)&hfrag[cur][0][ks][l * 8];
            al[ks] = *(const bf16x8*)&hfrag[cur][1][ks][l * 8];
        }

        // 2. recurrent MFMAs (dep distance 6: q innermost)
        f32x4 racc[6];
        #pragma unroll
        for (int q = 0; q < 6; ++q) { racc[q][0] = 0.f; racc[q][1] = 0.f; racc[q][2] = 0.f; racc[q][3] = 0.f; }
        #pragma unroll
        for (int ks = 0; ks < 4; ++ks) {
            bf16x8 bh[6], bl[6];
            #pragma unroll
            for (int q = 0; q < 6; ++q) {
                __builtin_memcpy(&bh[q], &Bh4[q][ks], 16);
                __builtin_memcpy(&bl[q], &Bl4[q][ks], 16);
            }
            #pragma unroll
            for (int q = 0; q < 6; ++q) racc[q] = MFMA16(ah[ks], bh[q], racc[q]);
            #pragma unroll
            for (int q = 0; q < 6; ++q) racc[q] = MFMA16(al[ks], bh[q], racc[q]);
            #pragma unroll
            for (int q = 0; q < 6; ++q) racc[q] = MFMA16(ah[ks], bl[q], racc[q]);
        }

        // 3. gates (xacc holds xp(si) from previous iteration)
        float hnew[2][4];
        #pragma unroll
        for (int cp = 0; cp < 2; ++cp)
            #pragma unroll
            for (int r = 0; r < 4; ++r) {
                float gr = sigm_(racc[cp][r]     + xacc[cp][r]     + bR[cp]);
                float gz = sigm_(racc[2 + cp][r] + xacc[2 + cp][r] + bZ[cp]);
                float gn = tanhf_((xacc[4 + cp][r] + bIN[cp]) + gr * (racc[4 + cp][r] + bHN[cp]));
                float hv = gn + gz * (hold[cp][r] - gn);
                hnew[cp][r] = hv;
                hold[cp][r] = hv;
            }

        // 4. convert x(si+1) raw -> hi/lo frags (vmcnt wait happens here)
        #pragma unroll
        for (int ks = 0; ks < 4; ++ks) {
            float f[8] = { xr0[ks].x, xr0[ks].y, xr0[ks].z, xr0[ks].w, xr1[ks].x, xr1[ks].y, xr1[ks].z, xr1[ks].w };
            bf16x8 vh, vl;
            #pragma unroll
            for (int j = 0; j < 8; ++j) {
                short hi = bf16_rne(f[j]);
                vh[j] = hi; vl[j] = bf16_rne(f[j] - bf16_tof(hi));
            }
            xh[ks] = vh; xl[ks] = vl;
        }
        // 5. issue x(si+2) loads (consumed next iteration)
        {
            const float* p = xbase + (size_t)txc * (CC * HH);
            #pragma unroll
            for (int ks = 0; ks < 4; ++ks) { xr0[ks] = *(const float4*)(p + ks * 32); xr1[ks] = *(const float4*)(p + ks * 32 + 4); }
            txc = (txc + 1 == LL) ? 0 : txc + 1;
        }

        // 6. h split -> hfrag[nxt] (all lanes incl. row-dups)
        #pragma unroll
        for (int cp = 0; cp < 2; ++cp)
            #pragma unroll
            for (int r = 0; r < 4; ++r) {
                short hi = bf16_rne(hold[cp][r]);
                short lo = bf16_rne(hold[cp][r] - bf16_tof(hi));
                int slot = (l4 * 4 + r + 16 * (2 * cp + (l15 >> 3))) * 8 + (l15 & 7);
                hfrag[nxt][0][w][slot] = hi;
                hfrag[nxt][1][w][slot] = lo;
            }

        // 7. out stores (lanes l4<2 cover b 0..7 exactly once)
        if (l4 < 2) {
            #pragma unroll
            for (int r = 0; r < 4; ++r) {
                int t = tcur[r];
                int valid = t < lenr[r];
                float* op = outb0 + r * outrow + (size_t)t * HH;
                op[0]  = valid ? hnew[0][r] : 0.0f;
                op[16] = valid ? hnew[1][r] : 0.0f;
            }
        }
        #pragma unroll
        for (int r = 0; r < 4; ++r) tcur[r] = (tcur[r] + 1 == LL) ? 0 : tcur[r] + 1;

        // 8. xproj for si+1 (overwrites consumed xacc; overlaps barrier)
        #pragma unroll
        for (int q = 0; q < 6; ++q) { xacc[q][0] = 0.f; xacc[q][1] = 0.f; xacc[q][2] = 0.f; xacc[q][3] = 0.f; }
        #pragma unroll
        for (int ks = 0; ks < 4; ++ks) {
            #pragma unroll
            for (int q = 0; q < 6; ++q) {
                int NT = (q < 2) ? (2 * w + q) : (q < 4) ? (8 + 2 * w + (q - 2)) : (16 + 2 * w + (q - 4));
                bf16x8 wv = *(const bf16x8*)&wfrag[NT][ks][l * 8];
                xacc[q] = MFMA16(xh[ks], wv, xacc[q]);
                xacc[q] = MFMA16(xl[ks], wv, xacc[q]);
            }
        }

        // 9. lgkm-only drain + raw barrier (x loads / out stores stay in flight)
        asm volatile("s_waitcnt lgkmcnt(0)" ::: "memory");
        __builtin_amdgcn_s_barrier();
        __builtin_amdgcn_sched_barrier(0);
        asm volatile("" ::: "memory");
    }
}

extern "C" void kernel_launch(void* const* d_in, const int* in_sizes, int n_in,
                              void* d_out, int out_size, void* d_ws, size_t ws_size,
                              hipStream_t stream) {
    const float* seqs  = (const float*)d_in[0];
    const unsigned char* tmask = (const unsigned char*)d_in[1];
    // d_in[2] = attention_mask (all false, unused)
    const float* W_ih  = (const float*)d_in[3];
    const float* W_hh  = (const float*)d_in[4];
    const float* b_ih  = (const float*)d_in[5];
    const float* b_hh  = (const float*)d_in[6];
    float* out = (float*)d_out;

    char* ws = (char*)d_ws;
    int*   lens   = (int*)(ws);                     // 1 KB
    short* wih_hi = (short*)(ws + 1024);            // 384 KB each
    short* whh_hi = (short*)(ws + 1024 + 393216);
    short* whh_lo = (short*)(ws + 1024 + 2 * 393216);

    compute_lens_kernel<<<1, BB, 0, stream>>>(tmask, lens);
    wsplit_kernel<<<768, 256, 0, stream>>>(W_ih, W_hh, wih_hi, whh_hi, whh_lo);

    gru_fused_kernel<<<dim3(32, CC), 256, 0, stream>>>(
        seqs, lens, wih_hi, whh_hi, whh_lo, b_ih, b_hh, out);
}

// Round 5
// 459.088 us; speedup vs baseline: 1.2889x; 1.2889x over previous
//
#include <hip/hip_runtime.h>
#include <hip/hip_bf16.h>

#define BB 256
#define LL 200
#define CC 4
#define HH 128
#define G3 384

typedef short bf16x8 __attribute__((ext_vector_type(8)));
typedef float f32x4 __attribute__((ext_vector_type(4)));

#define MFMA16(a, b, c) __builtin_amdgcn_mfma_f32_16x16x32_bf16((a), (b), (c), 0, 0, 0)

__device__ __forceinline__ short bf16_rne(float x) {
    union { float f; unsigned u; } v; v.f = x;
    unsigned r = v.u + 0x7FFFu + ((v.u >> 16) & 1u);
    return (short)(r >> 16);
}
__device__ __forceinline__ float bf16_tof(short b) {
    union { unsigned u; float f; } v; v.u = ((unsigned)(unsigned short)b) << 16;
    return v.f;
}
__device__ __forceinline__ float rcp_(float x) { return __builtin_amdgcn_rcpf(x); }
__device__ __forceinline__ float sigm_(float x) { return rcp_(1.0f + __expf(-x)); }
__device__ __forceinline__ float tanhf_(float x) { return 2.0f * rcp_(1.0f + __expf(-2.0f * x)) - 1.0f; }

__device__ __forceinline__ void split8(const float4& u, const float4& v, bf16x8& h, bf16x8& lo) {
    float f[8] = { u.x, u.y, u.z, u.w, v.x, v.y, v.z, v.w };
    #pragma unroll
    for (int j = 0; j < 8; ++j) {
        short hi = bf16_rne(f[j]);
        h[j] = hi;
        lo[j] = bf16_rne(f[j] - bf16_tof(hi));
    }
}

// ---------------------------------------------------------------------------
// lengths from timeline_mask (bool-dtype detection, verified R1-R4)
// ---------------------------------------------------------------------------
__global__ void compute_lens_kernel(const unsigned char* __restrict__ mask8,
                                    int* __restrict__ lens) {
    __shared__ int bad;
    int b = threadIdx.x;
    if (b == 0) bad = 0;
    __syncthreads();
    int cnt8 = 0, prev = 0, mono = 1;
    for (int t = 0; t < LL; ++t) {
        int v = mask8[b * LL + t] ? 1 : 0;
        cnt8 += (v == 0);
        if (v < prev) mono = 0;
        prev = v;
    }
    if (!mono) atomicAdd(&bad, 1);
    __syncthreads();
    int len;
    if (bad == 0) {
        len = cnt8;
    } else {
        const int* m32 = (const int*)mask8;
        int c = 0;
        for (int t = 0; t < LL; ++t) c += (m32[b * LL + t] == 0);
        len = c;
    }
    if (len < 1) len = 1;
    if (len > LL) len = LL;
    lens[b] = len;
}

// ---------------------------------------------------------------------------
// weight split: hi-only bf16 for both W_ih and W_hh
// ---------------------------------------------------------------------------
__global__ void wsplit_kernel(const float* __restrict__ Wih, const float* __restrict__ Whh,
                              short* __restrict__ wih_hi, short* __restrict__ whh_hi) {
    int i = blockIdx.x * 256 + threadIdx.x;   // 768 blocks -> 196608 = 4*384*128
    wih_hi[i] = bf16_rne(Wih[i]);
    whh_hi[i] = bf16_rne(Whh[i]);
}

// ---------------------------------------------------------------------------
// presplit: pre-roll + hi/lo split + A-frag-order x into ws.
// Layout per (c,bt,s): 64 lanes x 64 shorts = 8KB; lane holds
// [hi ks0..3 (8 shorts each)][lo ks0..3], element = x[row=l&15][k=ks*32+(l>>4)*8+j]
// ---------------------------------------------------------------------------
__global__ __launch_bounds__(256) void presplit_kernel(
    const float* __restrict__ seqs, const int* __restrict__ lens,
    short* __restrict__ xsplit)
{
    const int qx = blockIdx.x;         // 0..49
    const int bt = blockIdx.y;         // 0..15
    const int c  = blockIdx.z;         // 0..3
    const int tid = threadIdx.x;
    const int f = tid >> 6;            // 0..3
    const int lane = tid & 63;
    const int s = qx * 4 + f;
    const int row = lane & 15, gg = lane >> 4;
    const int b = bt * 16 + row;
    const int len = lens[b];
    int tt = s + LL - len; if (tt >= LL) tt -= LL;

    const float* src = seqs + ((size_t)(b * LL + tt) * CC + c) * HH + gg * 8;
    short* dst = xsplit + ((size_t)((c * 16 + bt) * 200 + s)) * 4096 + (size_t)lane * 64;

    #pragma unroll
    for (int ks = 0; ks < 4; ++ks) {
        float4 a0 = *(const float4*)(src + ks * 32);
        float4 a1 = *(const float4*)(src + ks * 32 + 4);
        bf16x8 vh, vl;
        split8(a0, a1, vh, vl);
        *(bf16x8*)(dst + ks * 8)      = vh;
        *(bf16x8*)(dst + 32 + ks * 8) = vl;
    }
}

// ---------------------------------------------------------------------------
// Fused GRU: 64 WGs (16 bt x 4 c), 512 thr = 8 waves, M=16 rows.
// Wave w owns gate-cols [16w,16w+16) via NT tiles {w, w+8, w+16}.
// Pinned per lane: 48 VGPR W_hh-hi + 48 VGPR W_ih-hi (fits 256-cap, no spill).
// rec = (h_hi + h_lo) x W_hh-hi ; xproj = (x_hi + x_lo) x W_ih-hi.
// h double-buffered in LDS A-frag layout; one raw barrier/step (lgkm-only).
// ---------------------------------------------------------------------------
template<bool PRESPLIT>
__global__ __launch_bounds__(512, 2) void gru_fused_kernel(
    const float* __restrict__ seqs,
    const short* __restrict__ xsplit,
    const int*   __restrict__ lens,
    const short* __restrict__ wih_hi,
    const short* __restrict__ whh_hi,
    const float* __restrict__ b_ih,
    const float* __restrict__ b_hh,
    float*       __restrict__ out)
{
    const int bt = blockIdx.x;          // 0..15
    const int c  = blockIdx.y;          // 0..3
    const int bbase = bt * 16;
    const int tid = threadIdx.x;
    const int l = tid & 63, w = tid >> 6;
    const int l15 = l & 15, g = l >> 4;

    __shared__ __align__(16) short hfrag[2][2][4][512];   // 16 KB

    // ---- pinned weight fragments (B-frag: row NT*16+l15, k = ks*32+g*8+j) ----
    float4 BH[3][4], WI[3][4];
    #pragma unroll
    for (int q = 0; q < 3; ++q) {
        const int NT = w + 8 * q;
        #pragma unroll
        for (int ks = 0; ks < 4; ++ks) {
            size_t off = (size_t)(c * G3 + NT * 16 + l15) * HH + ks * 32 + g * 8;
            BH[q][ks] = *(const float4*)(whh_hi + off);
            WI[q][ks] = *(const float4*)(wih_hi + off);
            asm volatile("" : "+v"(BH[q][ks].x), "+v"(BH[q][ks].y), "+v"(BH[q][ks].z), "+v"(BH[q][ks].w));
            asm volatile("" : "+v"(WI[q][ks].x), "+v"(WI[q][ks].y), "+v"(WI[q][ks].z), "+v"(WI[q][ks].w));
        }
    }

    // ---- zero h frag buffer 0 (first 4096 shorts) ----
    for (int i = tid; i < 4096; i += 512) ((short*)hfrag)[i] = 0;

    // ---- biases (one col per lane) ----
    const int col = 16 * w + l15;
    const float bR  = b_hh[c * G3 + col]       + b_ih[c * G3 + col];
    const float bZ  = b_hh[c * G3 + 128 + col] + b_ih[c * G3 + 128 + col];
    const float bHN = b_hh[c * G3 + 256 + col];
    const float bIN = b_ih[c * G3 + 256 + col];

    // ---- per-lane row state (C/D rows g*4+r) ----
    int lenr[4], tcur[4];
    #pragma unroll
    for (int r = 0; r < 4; ++r) {
        lenr[r] = lens[bbase + g * 4 + r];
        tcur[r] = LL - lenr[r];
    }
    float hold[4] = { 0.f, 0.f, 0.f, 0.f };

    // ---- x pipeline prologue ----
    bf16x8 xh[4], xl[4];
    const short* xptr = nullptr;
    const float* xrow = nullptr;
    float4 a0[4], a1[4];
    int txc = 0;

    if constexpr (PRESPLIT) {
        xptr = xsplit + ((size_t)(c * 16 + bt) * 200) * 4096 + (size_t)l * 64;
        #pragma unroll
        for (int ks = 0; ks < 4; ++ks) {
            xh[ks] = *(const bf16x8*)(xptr + ks * 8);
            xl[ks] = *(const bf16x8*)(xptr + 32 + ks * 8);
        }
    } else {
        const int lenx = lens[bbase + l15];
        xrow = seqs + ((size_t)(bbase + l15) * LL * CC + c) * HH + g * 8;
        txc = LL - lenx;
        {
            const float* p = xrow + (size_t)txc * (CC * HH);
            #pragma unroll
            for (int ks = 0; ks < 4; ++ks) { a0[ks] = *(const float4*)(p + ks * 32); a1[ks] = *(const float4*)(p + ks * 32 + 4); }
            txc = (txc + 1 == LL) ? 0 : txc + 1;
        }
        #pragma unroll
        for (int ks = 0; ks < 4; ++ks) split8(a0[ks], a1[ks], xh[ks], xl[ks]);
    }

    // xproj -> xacc(0)
    f32x4 xacc[3];
    #pragma unroll
    for (int q = 0; q < 3; ++q) { xacc[q][0] = 0.f; xacc[q][1] = 0.f; xacc[q][2] = 0.f; xacc[q][3] = 0.f; }
    #pragma unroll
    for (int ks = 0; ks < 4; ++ks) {
        bf16x8 wv[3];
        #pragma unroll
        for (int q = 0; q < 3; ++q) __builtin_memcpy(&wv[q], &WI[q][ks], 16);
        #pragma unroll
        for (int q = 0; q < 3; ++q) xacc[q] = MFMA16(xh[ks], wv[q], xacc[q]);
        #pragma unroll
        for (int q = 0; q < 3; ++q) xacc[q] = MFMA16(xl[ks], wv[q], xacc[q]);
    }

    // frags for step 1 (presplit: load; fallback: load raw + convert)
    if constexpr (PRESPLIT) {
        #pragma unroll
        for (int ks = 0; ks < 4; ++ks) {
            xh[ks] = *(const bf16x8*)(xptr + 4096 + ks * 8);
            xl[ks] = *(const bf16x8*)(xptr + 4096 + 32 + ks * 8);
        }
    } else {
        {
            const float* p = xrow + (size_t)txc * (CC * HH);
            #pragma unroll
            for (int ks = 0; ks < 4; ++ks) { a0[ks] = *(const float4*)(p + ks * 32); a1[ks] = *(const float4*)(p + ks * 32 + 4); }
            txc = (txc + 1 == LL) ? 0 : txc + 1;
        }
        #pragma unroll
        for (int ks = 0; ks < 4; ++ks) split8(a0[ks], a1[ks], xh[ks], xl[ks]);
        // issue raw x(2)
        {
            const float* p = xrow + (size_t)txc * (CC * HH);
            #pragma unroll
            for (int ks = 0; ks < 4; ++ks) { a0[ks] = *(const float4*)(p + ks * 32); a1[ks] = *(const float4*)(p + ks * 32 + 4); }
            txc = (txc + 1 == LL) ? 0 : txc + 1;
        }
    }

    __syncthreads();   // hfrag[0] + everything ready

    // =======================  main loop  =======================
    for (int si = 0; si < LL; ++si) {
        const int cur = si & 1, nxt = cur ^ 1;

        // 1. h A-frags (conflict-free b128)
        bf16x8 ah[4], al[4];
        #pragma unroll
        for (int ks = 0; ks < 4; ++ks) {
            ah[ks] = *(const bf16x8*)&hfrag[cur][0][ks][l * 8];
            al[ks] = *(const bf16x8*)&hfrag[cur][1][ks][l * 8];
        }

        // 2. rec MFMAs: racc = (h_hi + h_lo) . W_hh_hi
        f32x4 racc[3];
        #pragma unroll
        for (int q = 0; q < 3; ++q) { racc[q][0] = 0.f; racc[q][1] = 0.f; racc[q][2] = 0.f; racc[q][3] = 0.f; }
        #pragma unroll
        for (int ks = 0; ks < 4; ++ks) {
            bf16x8 bv[3];
            #pragma unroll
            for (int q = 0; q < 3; ++q) __builtin_memcpy(&bv[q], &BH[q][ks], 16);
            #pragma unroll
            for (int q = 0; q < 3; ++q) racc[q] = MFMA16(ah[ks], bv[q], racc[q]);
            #pragma unroll
            for (int q = 0; q < 3; ++q) racc[q] = MFMA16(al[ks], bv[q], racc[q]);
        }

        // 3. gates (xacc = xp(si))
        float hnew[4];
        #pragma unroll
        for (int r = 0; r < 4; ++r) {
            float gr = sigm_(racc[0][r] + xacc[0][r] + bR);
            float gz = sigm_(racc[1][r] + xacc[1][r] + bZ);
            float gn = tanhf_((xacc[2][r] + bIN) + gr * (racc[2][r] + bHN));
            float hv = gn + gz * (hold[r] - gn);
            hnew[r] = hv;
            hold[r] = hv;
        }

        // 4. xproj -> xacc(si+1) (frags hold x(si+1))
        #pragma unroll
        for (int q = 0; q < 3; ++q) { xacc[q][0] = 0.f; xacc[q][1] = 0.f; xacc[q][2] = 0.f; xacc[q][3] = 0.f; }
        #pragma unroll
        for (int ks = 0; ks < 4; ++ks) {
            bf16x8 wv[3];
            #pragma unroll
            for (int q = 0; q < 3; ++q) __builtin_memcpy(&wv[q], &WI[q][ks], 16);
            #pragma unroll
            for (int q = 0; q < 3; ++q) xacc[q] = MFMA16(xh[ks], wv[q], xacc[q]);
            #pragma unroll
            for (int q = 0; q < 3; ++q) xacc[q] = MFMA16(xl[ks], wv[q], xacc[q]);
        }

        // 5. next x frags (issued now, consumed next iter -> full-step latency)
        if constexpr (PRESPLIT) {
            int s2 = si + 2; s2 = (s2 < LL) ? s2 : LL - 1;
            const short* p = xptr + (size_t)s2 * 4096;
            #pragma unroll
            for (int ks = 0; ks < 4; ++ks) {
                xh[ks] = *(const bf16x8*)(p + ks * 8);
                xl[ks] = *(const bf16x8*)(p + 32 + ks * 8);
            }
        } else {
            // convert raw x(si+2) -> frags; issue raw x(si+3)
            #pragma unroll
            for (int ks = 0; ks < 4; ++ks) split8(a0[ks], a1[ks], xh[ks], xl[ks]);
            const float* p = xrow + (size_t)txc * (CC * HH);
            #pragma unroll
            for (int ks = 0; ks < 4; ++ks) { a0[ks] = *(const float4*)(p + ks * 32); a1[ks] = *(const float4*)(p + ks * 32 + 4); }
            txc = (txc + 1 == LL) ? 0 : txc + 1;
        }

        // 6. h split -> hfrag[nxt]
        {
            const int ksw = w >> 1;
            const int gp  = (w & 1) * 2 + (l15 >> 3);
            const int jj  = l15 & 7;
            #pragma unroll
            for (int r = 0; r < 4; ++r) {
                const int row = g * 4 + r;
                short hi = bf16_rne(hold[r]);
                short lo = bf16_rne(hold[r] - bf16_tof(hi));
                const int slot = (row + 16 * gp) * 8 + jj;
                hfrag[nxt][0][ksw][slot] = hi;
                hfrag[nxt][1][ksw][slot] = lo;
            }
        }

        // 7. out stores (scatter to t, zero-masked; stays in flight past barrier)
        #pragma unroll
        for (int r = 0; r < 4; ++r) {
            const int t = tcur[r];
            const int valid = t < lenr[r];
            out[((size_t)(c * BB + bbase + g * 4 + r) * LL + t) * HH + col] = valid ? hnew[r] : 0.0f;
            tcur[r] = (t + 1 == LL) ? 0 : t + 1;
        }

        // 8. lgkm-only drain + raw barrier (vmcnt ops stay in flight)
        asm volatile("s_waitcnt lgkmcnt(0)" ::: "memory");
        __builtin_amdgcn_s_barrier();
        __builtin_amdgcn_sched_barrier(0);
        asm volatile("" ::: "memory");
    }
}

extern "C" void kernel_launch(void* const* d_in, const int* in_sizes, int n_in,
                              void* d_out, int out_size, void* d_ws, size_t ws_size,
                              hipStream_t stream) {
    const float* seqs  = (const float*)d_in[0];
    const unsigned char* tmask = (const unsigned char*)d_in[1];
    // d_in[2] = attention_mask (all false, unused)
    const float* W_ih  = (const float*)d_in[3];
    const float* W_hh  = (const float*)d_in[4];
    const float* b_ih  = (const float*)d_in[5];
    const float* b_hh  = (const float*)d_in[6];
    float* out = (float*)d_out;

    char* ws = (char*)d_ws;
    int*   lens   = (int*)(ws);                         // 1 KB
    short* wih_hi = (short*)(ws + 1024);                // 384 KB
    short* whh_hi = (short*)(ws + 1024 + 393216);       // 384 KB
    short* xsplit = (short*)(ws + 787456);              // 100 MB (optional)

    const size_t need_presplit = 787456ull + 104857600ull;
    const bool presplit = (ws_size >= need_presplit);

    compute_lens_kernel<<<1, BB, 0, stream>>>(tmask, lens);
    wsplit_kernel<<<768, 256, 0, stream>>>(W_ih, W_hh, wih_hi, whh_hi);

    if (presplit) {
        presplit_kernel<<<dim3(50, 16, CC), 256, 0, stream>>>(seqs, lens, xsplit);
        gru_fused_kernel<true><<<dim3(16, CC), 512, 0, stream>>>(
            seqs, xsplit, lens, wih_hi, whh_hi, b_ih, b_hh, out);
    } else {
        gru_fused_kernel<false><<<dim3(16, CC), 512, 0, stream>>>(
            seqs, nullptr, lens, wih_hi, whh_hi, b_ih, b_hh, out);
    }
}

// Round 6
// 312.830 us; speedup vs baseline: 1.8915x; 1.4675x over previous
//
#include <hip/hip_runtime.h>
#include <hip/hip_bf16.h>

#define BB 256
#define LL 200
#define CC 4
#define HH 128
#define G3 384

typedef short bf16x8 __attribute__((ext_vector_type(8)));
typedef float f32x4 __attribute__((ext_vector_type(4)));

#define MFMA16(a, b, c) __builtin_amdgcn_mfma_f32_16x16x32_bf16((a), (b), (c), 0, 0, 0)
#define PIN4(v) asm volatile("" : "+v"((v).x), "+v"((v).y), "+v"((v).z), "+v"((v).w))

__device__ __forceinline__ short bf16_rne(float x) {
    union { float f; unsigned u; } v; v.f = x;
    unsigned r = v.u + 0x7FFFu + ((v.u >> 16) & 1u);
    return (short)(r >> 16);
}
__device__ __forceinline__ float bf16_tof(short b) {
    union { unsigned u; float f; } v; v.u = ((unsigned)(unsigned short)b) << 16;
    return v.f;
}
__device__ __forceinline__ float rcp_(float x) { return __builtin_amdgcn_rcpf(x); }
__device__ __forceinline__ float sigm_(float x) { return rcp_(1.0f + __expf(-x)); }
__device__ __forceinline__ float tanhf_(float x) { return 2.0f * rcp_(1.0f + __expf(-2.0f * x)) - 1.0f; }

// ---------------------------------------------------------------------------
// lengths from timeline_mask (bool-dtype detection, verified R1-R5)
// ---------------------------------------------------------------------------
__global__ void compute_lens_kernel(const unsigned char* __restrict__ mask8,
                                    int* __restrict__ lens) {
    __shared__ int bad;
    int b = threadIdx.x;
    if (b == 0) bad = 0;
    __syncthreads();
    int cnt8 = 0, prev = 0, mono = 1;
    for (int t = 0; t < LL; ++t) {
        int v = mask8[b * LL + t] ? 1 : 0;
        cnt8 += (v == 0);
        if (v < prev) mono = 0;
        prev = v;
    }
    if (!mono) atomicAdd(&bad, 1);
    __syncthreads();
    int len;
    if (bad == 0) {
        len = cnt8;
    } else {
        const int* m32 = (const int*)mask8;
        int c = 0;
        for (int t = 0; t < LL; ++t) c += (m32[b * LL + t] == 0);
        len = c;
    }
    if (len < 1) len = 1;
    if (len > LL) len = LL;
    lens[b] = len;
}

// ---------------------------------------------------------------------------
// weight split: W_hh -> hi + lo residual; W_ih -> hi only
// ---------------------------------------------------------------------------
__global__ void wsplit_kernel(const float* __restrict__ Wih, const float* __restrict__ Whh,
                              short* __restrict__ wih_hi,
                              short* __restrict__ whh_hi, short* __restrict__ whh_lo) {
    int i = blockIdx.x * 256 + threadIdx.x;   // 768 blocks -> 196608
    wih_hi[i] = bf16_rne(Wih[i]);
    float b = Whh[i];
    short hb = bf16_rne(b);
    whh_hi[i] = hb;
    whh_lo[i] = bf16_rne(b - bf16_tof(hb));
}

// ---------------------------------------------------------------------------
// Fused GRU: grid (32 bt x 4 c) = 128 WGs, 512 thr = 8 waves, M=8 batches.
// Wave w owns gate-cols [16w,16w+16) via NT tiles {w, w+8, w+16}.
// Pinned per lane (in-loop asm pin => loop-carried, no remat):
//   W_hh-hi 48 VGPR + W_ih-hi 48 VGPR.
// A-frag rows replicated 2x: row -> batch row&7.
// h: hi+lo shorts in LDS, double-buffered, writer-side split.
// x: hi-only bf16 staged cooperatively into LDS one step ahead; xproj for
//    s+1 computed during step s (off the recurrence chain).
// ---------------------------------------------------------------------------
__global__ __launch_bounds__(512, 2) void gru_fused_kernel(
    const float* __restrict__ seqs,    // (B,L,C,H)
    const int*   __restrict__ lens,    // (B,)
    const short* __restrict__ wih_hi,  // (C,384,128) bf16
    const short* __restrict__ whh_hi,  // (C,384,128) bf16
    const short* __restrict__ whh_lo,
    const float* __restrict__ b_ih,    // (C,384)
    const float* __restrict__ b_hh,    // (C,384)
    float*       __restrict__ out)     // (C,B,L,H)
{
    const int bt = blockIdx.x;             // 0..31
    const int c  = blockIdx.y;             // 0..3
    const int bbase = bt * 8;
    const int tid = threadIdx.x;           // 0..511
    const int w = tid >> 6;                // wave 0..7
    const int l = tid & 63;
    const int l15 = l & 15, g = l >> 4;
    const int lb  = l15 & 7;               // A-row batch (replicated)

    __shared__ __align__(16) short hA[2][2][8][136];   // [buf][hi/lo][batch][k]
    __shared__ __align__(16) short xs[2][8][136];      // [buf][batch][k] bf16 hi

    // ---- pinned weight fragments: B-frag row NT*16+l15, k = ks*32+g*8+j ----
    float4 BH[3][4], WI[3][4];
    #pragma unroll
    for (int q = 0; q < 3; ++q) {
        const int NT = w + 8 * q;
        #pragma unroll
        for (int ks = 0; ks < 4; ++ks) {
            size_t off = (size_t)(c * G3 + NT * 16 + l15) * HH + ks * 32 + g * 8;
            BH[q][ks] = *(const float4*)(whh_hi + off);
            WI[q][ks] = *(const float4*)(wih_hi + off);
        }
    }
    float4 BL0[4];   // W_hh lo, used only... (dropped: hi-only W_hh proven R5)
    (void)BL0;

    // ---- stager state: wave w loads batch row bbase+w, 2 floats/thread ----
    const int bs = bbase + w;
    const int k0 = (l) * 2;                 // 0..126
    const int lenS = lens[bs];
    const float* srow = seqs + ((size_t)bs * LL * CC + c) * HH + k0;
    int ts0 = LL - lenS;                    // t for s=0
    int ts1 = ts0 + 1; if (ts1 >= LL) ts1 -= LL;
    float2 xr0 = *(const float2*)(srow + (size_t)ts0 * (CC * HH));
    float2 xr1 = *(const float2*)(srow + (size_t)ts1 * (CC * HH));
    int txs = ts1 + 1; if (txs >= LL) txs -= LL;   // t for s=2

    // ---- biases (per-lane col), folded into accumulator inits ----
    const int col = 16 * w + l15;
    const float bRs = b_hh[c * G3 + col]       + b_ih[c * G3 + col];
    const float bZs = b_hh[c * G3 + 128 + col] + b_ih[c * G3 + 128 + col];
    const float bHN = b_hh[c * G3 + 256 + col];
    const float bIN = b_ih[c * G3 + 256 + col];

    // ---- per-lane output row state (valid for l4<2: batches l4*4+r) ----
    const int l4 = l >> 4;
    int lenr[4], tcur[4];
    #pragma unroll
    for (int r = 0; r < 4; ++r) {
        int b = bbase + (l4 & 1) * 4 + r;
        lenr[r] = lens[b];
        tcur[r] = LL - lenr[r];
    }
    float hold[4] = { 0.f, 0.f, 0.f, 0.f };

    // ---- zero h buffer 0 ----
    for (int i = tid; i < 2 * 8 * 136; i += 512) ((short*)hA[0])[i] = 0;

    // ---- stage x(0)->xs[0], x(1)->xs[1] ----
    {
        unsigned p0 = (unsigned)(unsigned short)bf16_rne(xr0.x) |
                      ((unsigned)(unsigned short)bf16_rne(xr0.y) << 16);
        unsigned p1 = (unsigned)(unsigned short)bf16_rne(xr1.x) |
                      ((unsigned)(unsigned short)bf16_rne(xr1.y) << 16);
        *(unsigned*)&xs[0][w][k0] = p0;
        *(unsigned*)&xs[1][w][k0] = p1;
    }
    __syncthreads();

    // ---- xacc(0) from xs[0] ----
    f32x4 xacc[3];
    xacc[0] = (f32x4){bRs, bRs, bRs, bRs};   // R: fold both biases
    xacc[1] = (f32x4){bZs, bZs, bZs, bZs};   // Z
    xacc[2] = (f32x4){bIN, bIN, bIN, bIN};   // N x-side
    {
        bf16x8 xh[4];
        #pragma unroll
        for (int ks = 0; ks < 4; ++ks)
            xh[ks] = *(const bf16x8*)&xs[0][lb][ks * 32 + g * 8];
        #pragma unroll
        for (int ks = 0; ks < 4; ++ks) {
            #pragma unroll
            for (int q = 0; q < 3; ++q) {
                bf16x8 wv; __builtin_memcpy(&wv, &WI[q][ks], 16);
                xacc[q] = MFMA16(xh[ks], wv, xacc[q]);
            }
        }
    }
    // issue x(2)
    float2 xraw = *(const float2*)(srow + (size_t)txs * (CC * HH));
    txs = (txs + 1 == LL) ? 0 : txs + 1;

    __syncthreads();   // protect xs[0] from step-0 overwrite

    // =======================  main loop  =======================
    for (int si = 0; si < LL; ++si) {
        const int hb = si & 1, hn = hb ^ 1;

        // pin weights (loop-carried through volatile asm -> no remat/spill)
        #pragma unroll
        for (int q = 0; q < 3; ++q) {
            #pragma unroll
            for (int ks = 0; ks < 4; ++ks) { PIN4(BH[q][ks]); PIN4(WI[q][ks]); }
        }

        // 1. h A-frags (hi+lo)
        bf16x8 ah[4], al[4];
        #pragma unroll
        for (int ks = 0; ks < 4; ++ks) {
            ah[ks] = *(const bf16x8*)&hA[hb][0][lb][ks * 32 + g * 8];
            al[ks] = *(const bf16x8*)&hA[hb][1][lb][ks * 32 + g * 8];
        }
        // 2. x(si+1) A-frags (hi only, pre-staged bf16)
        bf16x8 xh[4];
        #pragma unroll
        for (int ks = 0; ks < 4; ++ks)
            xh[ks] = *(const bf16x8*)&xs[hn][lb][ks * 32 + g * 8];

        // 3. rec MFMAs: racc = (h_hi + h_lo) . W_hh_hi  (C-init = biases)
        f32x4 racc[3];
        racc[0] = (f32x4){0.f, 0.f, 0.f, 0.f};
        racc[1] = (f32x4){0.f, 0.f, 0.f, 0.f};
        racc[2] = (f32x4){bHN, bHN, bHN, bHN};
        #pragma unroll
        for (int ks = 0; ks < 4; ++ks) {
            bf16x8 bv[3];
            #pragma unroll
            for (int q = 0; q < 3; ++q) __builtin_memcpy(&bv[q], &BH[q][ks], 16);
            #pragma unroll
            for (int q = 0; q < 3; ++q) racc[q] = MFMA16(ah[ks], bv[q], racc[q]);
            #pragma unroll
            for (int q = 0; q < 3; ++q) racc[q] = MFMA16(al[ks], bv[q], racc[q]);
        }

        // 4. gates (xacc = xp(si) + folded biases)
        float hnew[4];
        #pragma unroll
        for (int r = 0; r < 4; ++r) {
            float gr = sigm_(racc[0][r] + xacc[0][r]);
            float gz = sigm_(racc[1][r] + xacc[1][r]);
            float gn = tanhf_(xacc[2][r] + gr * racc[2][r]);
            float hv = gn + gz * (hold[r] - gn);
            hnew[r] = hv;
            hold[r] = hv;
        }

        // 5. xproj for si+1 (off-chain; consumed next iteration)
        f32x4 xn[3];
        xn[0] = (f32x4){bRs, bRs, bRs, bRs};
        xn[1] = (f32x4){bZs, bZs, bZs, bZs};
        xn[2] = (f32x4){bIN, bIN, bIN, bIN};
        #pragma unroll
        for (int ks = 0; ks < 4; ++ks) {
            bf16x8 wv[3];
            #pragma unroll
            for (int q = 0; q < 3; ++q) __builtin_memcpy(&wv[q], &WI[q][ks], 16);
            #pragma unroll
            for (int q = 0; q < 3; ++q) xn[q] = MFMA16(xh[ks], wv[q], xn[q]);
        }
        xacc[0] = xn[0]; xacc[1] = xn[1]; xacc[2] = xn[2];

        // 6. h split -> hA[hn] (writer-side, lanes l4<2 cover 8 batches x col)
        if (l4 < 2) {
            #pragma unroll
            for (int r = 0; r < 4; ++r) {
                int b = l4 * 4 + r;
                short hi = bf16_rne(hold[r]);
                short lo = bf16_rne(hold[r] - bf16_tof(hi));
                hA[hn][0][b][col] = hi;
                hA[hn][1][b][col] = lo;
            }
            // 7. out stores (scatter to t, zero-masked; fire-and-forget)
            #pragma unroll
            for (int r = 0; r < 4; ++r) {
                int t = tcur[r];
                int valid = t < lenr[r];
                out[((size_t)(c * BB + bbase + l4 * 4 + r) * LL + t) * HH + col]
                    = valid ? hnew[r] : 0.0f;
            }
        }
        #pragma unroll
        for (int r = 0; r < 4; ++r) tcur[r] = (tcur[r] + 1 == LL) ? 0 : tcur[r] + 1;

        // 8. stage x(si+2) -> xs[hb] (raw regs loaded last iter; vmcnt auto)
        {
            unsigned p = (unsigned)(unsigned short)bf16_rne(xraw.x) |
                         ((unsigned)(unsigned short)bf16_rne(xraw.y) << 16);
            *(unsigned*)&xs[hb][w][k0] = p;
        }
        // 9. issue x(si+3) raw load (mod-L wrap keeps it in-bounds; tail reads
        //    are staged but never consumed)
        xraw = *(const float2*)(srow + (size_t)txs * (CC * HH));
        txs = (txs + 1 == LL) ? 0 : txs + 1;

        // 10. lgkm-only drain + raw barrier (out stores/x loads stay in flight)
        asm volatile("s_waitcnt lgkmcnt(0)" ::: "memory");
        __builtin_amdgcn_s_barrier();
        __builtin_amdgcn_sched_barrier(0);
        asm volatile("" ::: "memory");
    }
}

extern "C" void kernel_launch(void* const* d_in, const int* in_sizes, int n_in,
                              void* d_out, int out_size, void* d_ws, size_t ws_size,
                              hipStream_t stream) {
    const float* seqs  = (const float*)d_in[0];
    const unsigned char* tmask = (const unsigned char*)d_in[1];
    // d_in[2] = attention_mask (all false, unused)
    const float* W_ih  = (const float*)d_in[3];
    const float* W_hh  = (const float*)d_in[4];
    const float* b_ih  = (const float*)d_in[5];
    const float* b_hh  = (const float*)d_in[6];
    float* out = (float*)d_out;

    char* ws = (char*)d_ws;
    int*   lens   = (int*)(ws);                       // 1 KB
    short* wih_hi = (short*)(ws + 1024);              // 384 KB
    short* whh_hi = (short*)(ws + 1024 + 393216);     // 384 KB
    short* whh_lo = (short*)(ws + 1024 + 2 * 393216); // 384 KB

    compute_lens_kernel<<<1, BB, 0, stream>>>(tmask, lens);
    wsplit_kernel<<<768, 256, 0, stream>>>(W_ih, W_hh, wih_hi, whh_hi, whh_lo);

    gru_fused_kernel<<<dim3(32, CC), 512, 0, stream>>>(
        seqs, lens, wih_hi, whh_hi, whh_lo, b_ih, b_hh, out);
}

// Round 7
// 304.050 us; speedup vs baseline: 1.9461x; 1.0289x over previous
//
#include <hip/hip_runtime.h>
#include <hip/hip_bf16.h>

#define BB 256
#define LL 200
#define CC 4
#define HH 128
#define G3 384

typedef short bf16x8 __attribute__((ext_vector_type(8)));
typedef float f32x4 __attribute__((ext_vector_type(4)));

#define MFMA16(a, b, c) __builtin_amdgcn_mfma_f32_16x16x32_bf16((a), (b), (c), 0, 0, 0)

__device__ __forceinline__ short bf16_rne(float x) {
    union { float f; unsigned u; } v; v.f = x;
    unsigned r = v.u + 0x7FFFu + ((v.u >> 16) & 1u);
    return (short)(r >> 16);
}
__device__ __forceinline__ float bf16_tof(short b) {
    union { unsigned u; float f; } v; v.u = ((unsigned)(unsigned short)b) << 16;
    return v.f;
}
__device__ __forceinline__ float rcp_(float x) { return __builtin_amdgcn_rcpf(x); }
__device__ __forceinline__ float sigm_(float x) { return rcp_(1.0f + __expf(-x)); }
__device__ __forceinline__ float tanhf_(float x) { return 2.0f * rcp_(1.0f + __expf(-2.0f * x)) - 1.0f; }

// ---------------------------------------------------------------------------
// lengths from timeline_mask (bool-dtype detection, verified R1-R6)
// ---------------------------------------------------------------------------
__global__ void compute_lens_kernel(const unsigned char* __restrict__ mask8,
                                    int* __restrict__ lens) {
    __shared__ int bad;
    int b = threadIdx.x;
    if (b == 0) bad = 0;
    __syncthreads();
    int cnt8 = 0, prev = 0, mono = 1;
    for (int t = 0; t < LL; ++t) {
        int v = mask8[b * LL + t] ? 1 : 0;
        cnt8 += (v == 0);
        if (v < prev) mono = 0;
        prev = v;
    }
    if (!mono) atomicAdd(&bad, 1);
    __syncthreads();
    int len;
    if (bad == 0) {
        len = cnt8;
    } else {
        const int* m32 = (const int*)mask8;
        int c = 0;
        for (int t = 0; t < LL; ++t) c += (m32[b * LL + t] == 0);
        len = c;
    }
    if (len < 1) len = 1;
    if (len > LL) len = LL;
    lens[b] = len;
}

// ---------------------------------------------------------------------------
// weight split: bf16 hi for W_ih and W_hh
// ---------------------------------------------------------------------------
__global__ void wsplit_kernel(const float* __restrict__ Wih, const float* __restrict__ Whh,
                              short* __restrict__ wih_hi, short* __restrict__ whh_hi) {
    int i = blockIdx.x * 256 + threadIdx.x;   // 768 blocks -> 196608
    wih_hi[i] = bf16_rne(Wih[i]);
    whh_hi[i] = bf16_rne(Whh[i]);
}

// ---------------------------------------------------------------------------
// Fused GRU: grid (32 bt x 4 c) = 128 WGs, 512 thr = 8 waves, M=8 batches.
// Wave w owns gate-cols [16w,16w+16) via NT tiles {w, w+8, w+16}.
// Weights are PARKED as identity-MFMA results (D = 0*0 + C): the values are
// defined by an MFMA, so the register allocator CANNOT rematerialize them
// from global memory -- they must stay in VGPRs/AGPRs for the whole kernel.
// (Identity passthrough is bit-exact here: packed-bf16-pair words have the
// hi-bf16's exponent field as the f32 exponent -> always normal, no FTZ.)
// h: hi+lo shorts in LDS, double-buffered, writer-side split.
// x: hi-only bf16 staged cooperatively into LDS one step ahead; xproj for
//    s+1 computed during step s (off the recurrence chain).
// ---------------------------------------------------------------------------
__global__ __launch_bounds__(512, 2) void gru_fused_kernel(
    const float* __restrict__ seqs,    // (B,L,C,H)
    const int*   __restrict__ lens,    // (B,)
    const short* __restrict__ wih_hi,  // (C,384,128) bf16
    const short* __restrict__ whh_hi,  // (C,384,128) bf16
    const float* __restrict__ b_ih,    // (C,384)
    const float* __restrict__ b_hh,    // (C,384)
    float*       __restrict__ out)     // (C,B,L,H)
{
    const int bt = blockIdx.x;             // 0..31
    const int c  = blockIdx.y;             // 0..3
    const int bbase = bt * 8;
    const int tid = threadIdx.x;           // 0..511
    const int w = tid >> 6;                // wave 0..7
    const int l = tid & 63;
    const int l15 = l & 15, g = l >> 4;
    const int lb  = l15 & 7;               // A-row batch (replicated 2x)

    __shared__ __align__(16) short hA[2][2][8][136];   // [buf][hi/lo][batch][k]
    __shared__ __align__(16) short xs[2][8][136];      // [buf][batch][k] bf16 hi

    // ---- park weight fragments in registers via identity MFMA ----
    // B-frag: row NT*16+l15, k = ks*32 + g*8 + j
    bf16x8 BH[3][4], WI[3][4];
    {
        const bf16x8 z8 = (bf16x8){0, 0, 0, 0, 0, 0, 0, 0};
        #pragma unroll
        for (int q = 0; q < 3; ++q) {
            const int NT = w + 8 * q;
            #pragma unroll
            for (int ks = 0; ks < 4; ++ks) {
                size_t off = (size_t)(c * G3 + NT * 16 + l15) * HH + ks * 32 + g * 8;
                f32x4 th = *(const f32x4*)(const void*)(whh_hi + off);
                f32x4 ti = *(const f32x4*)(const void*)(wih_hi + off);
                f32x4 ph = MFMA16(z8, z8, th);   // D = C exactly; MFMA-defined => no remat
                f32x4 pi = MFMA16(z8, z8, ti);
                __builtin_memcpy(&BH[q][ks], &ph, 16);
                __builtin_memcpy(&WI[q][ks], &pi, 16);
            }
        }
    }

    // ---- stager state: wave w loads batch row bbase+w, 2 floats/thread ----
    const int bs = bbase + w;
    const int k0 = l * 2;                   // 0..126
    const int lenS = lens[bs];
    const float* srow = seqs + ((size_t)bs * LL * CC + c) * HH + k0;
    int ts0 = LL - lenS;                    // t for s=0
    int ts1 = ts0 + 1; if (ts1 >= LL) ts1 -= LL;
    float2 xr0 = *(const float2*)(srow + (size_t)ts0 * (CC * HH));
    float2 xr1 = *(const float2*)(srow + (size_t)ts1 * (CC * HH));
    int txs = ts1 + 1; if (txs >= LL) txs -= LL;   // t for s=2

    // ---- biases (per-lane col), folded into accumulator inits ----
    const int col = 16 * w + l15;
    const float bRs = b_hh[c * G3 + col]       + b_ih[c * G3 + col];
    const float bZs = b_hh[c * G3 + 128 + col] + b_ih[c * G3 + 128 + col];
    const float bHN = b_hh[c * G3 + 256 + col];
    const float bIN = b_ih[c * G3 + 256 + col];

    // ---- per-lane output row state (valid for l4<2: batches l4*4+r) ----
    const int l4 = l >> 4;
    int lenr[4], tcur[4];
    #pragma unroll
    for (int r = 0; r < 4; ++r) {
        int b = bbase + (l4 & 1) * 4 + r;
        lenr[r] = lens[b];
        tcur[r] = LL - lenr[r];
    }
    float hold[4] = { 0.f, 0.f, 0.f, 0.f };

    // ---- zero h buffer 0 ----
    for (int i = tid; i < 2 * 8 * 136; i += 512) ((short*)hA[0])[i] = 0;

    // ---- stage x(0)->xs[0], x(1)->xs[1] ----
    {
        unsigned p0 = (unsigned)(unsigned short)bf16_rne(xr0.x) |
                      ((unsigned)(unsigned short)bf16_rne(xr0.y) << 16);
        unsigned p1 = (unsigned)(unsigned short)bf16_rne(xr1.x) |
                      ((unsigned)(unsigned short)bf16_rne(xr1.y) << 16);
        *(unsigned*)&xs[0][w][k0] = p0;
        *(unsigned*)&xs[1][w][k0] = p1;
    }
    __syncthreads();

    // ---- xacc(0) from xs[0] ----
    f32x4 xacc[3];
    xacc[0] = (f32x4){bRs, bRs, bRs, bRs};
    xacc[1] = (f32x4){bZs, bZs, bZs, bZs};
    xacc[2] = (f32x4){bIN, bIN, bIN, bIN};
    {
        bf16x8 xh[4];
        #pragma unroll
        for (int ks = 0; ks < 4; ++ks)
            xh[ks] = *(const bf16x8*)&xs[0][lb][ks * 32 + g * 8];
        #pragma unroll
        for (int ks = 0; ks < 4; ++ks) {
            #pragma unroll
            for (int q = 0; q < 3; ++q)
                xacc[q] = MFMA16(xh[ks], WI[q][ks], xacc[q]);
        }
    }
    // issue x(2)
    float2 xraw = *(const float2*)(srow + (size_t)txs * (CC * HH));
    txs = (txs + 1 == LL) ? 0 : txs + 1;

    __syncthreads();   // protect xs[0] from step-0 overwrite

    // =======================  main loop  =======================
    for (int si = 0; si < LL; ++si) {
        const int hb = si & 1, hn = hb ^ 1;

        // 1. h A-frags (hi+lo)
        bf16x8 ah[4], al[4];
        #pragma unroll
        for (int ks = 0; ks < 4; ++ks) {
            ah[ks] = *(const bf16x8*)&hA[hb][0][lb][ks * 32 + g * 8];
            al[ks] = *(const bf16x8*)&hA[hb][1][lb][ks * 32 + g * 8];
        }
        // 2. x(si+1) A-frags (hi only, pre-staged bf16)
        bf16x8 xh[4];
        #pragma unroll
        for (int ks = 0; ks < 4; ++ks)
            xh[ks] = *(const bf16x8*)&xs[hn][lb][ks * 32 + g * 8];

        // 3. rec MFMAs: racc = (h_hi + h_lo) . W_hh_hi  (C-init = biases)
        f32x4 racc[3];
        racc[0] = (f32x4){0.f, 0.f, 0.f, 0.f};
        racc[1] = (f32x4){0.f, 0.f, 0.f, 0.f};
        racc[2] = (f32x4){bHN, bHN, bHN, bHN};
        #pragma unroll
        for (int ks = 0; ks < 4; ++ks) {
            #pragma unroll
            for (int q = 0; q < 3; ++q) racc[q] = MFMA16(ah[ks], BH[q][ks], racc[q]);
            #pragma unroll
            for (int q = 0; q < 3; ++q) racc[q] = MFMA16(al[ks], BH[q][ks], racc[q]);
        }

        // 4. gates (xacc = xp(si) + folded biases)
        float hnew[4];
        #pragma unroll
        for (int r = 0; r < 4; ++r) {
            float gr = sigm_(racc[0][r] + xacc[0][r]);
            float gz = sigm_(racc[1][r] + xacc[1][r]);
            float gn = tanhf_(xacc[2][r] + gr * racc[2][r]);
            float hv = gn + gz * (hold[r] - gn);
            hnew[r] = hv;
            hold[r] = hv;
        }

        // 5. xproj for si+1 (off-chain; consumed next iteration)
        xacc[0] = (f32x4){bRs, bRs, bRs, bRs};
        xacc[1] = (f32x4){bZs, bZs, bZs, bZs};
        xacc[2] = (f32x4){bIN, bIN, bIN, bIN};
        #pragma unroll
        for (int ks = 0; ks < 4; ++ks) {
            #pragma unroll
            for (int q = 0; q < 3; ++q)
                xacc[q] = MFMA16(xh[ks], WI[q][ks], xacc[q]);
        }

        // 6. h split -> hA[hn] (writer-side, lanes l4<2 cover 8 batches x col)
        if (l4 < 2) {
            #pragma unroll
            for (int r = 0; r < 4; ++r) {
                int b = l4 * 4 + r;
                short hi = bf16_rne(hold[r]);
                short lo = bf16_rne(hold[r] - bf16_tof(hi));
                hA[hn][0][b][col] = hi;
                hA[hn][1][b][col] = lo;
            }
            // 7. out stores (scatter to t, zero-masked; fire-and-forget)
            #pragma unroll
            for (int r = 0; r < 4; ++r) {
                int t = tcur[r];
                int valid = t < lenr[r];
                out[((size_t)(c * BB + bbase + l4 * 4 + r) * LL + t) * HH + col]
                    = valid ? hnew[r] : 0.0f;
            }
        }
        #pragma unroll
        for (int r = 0; r < 4; ++r) tcur[r] = (tcur[r] + 1 == LL) ? 0 : tcur[r] + 1;

        // 8. stage x(si+2) -> xs[hb] (raw regs loaded last iter; vmcnt auto)
        {
            unsigned p = (unsigned)(unsigned short)bf16_rne(xraw.x) |
                         ((unsigned)(unsigned short)bf16_rne(xraw.y) << 16);
            *(unsigned*)&xs[hb][w][k0] = p;
        }
        // 9. issue x(si+3) raw load (mod-L wrap keeps it in-bounds)
        xraw = *(const float2*)(srow + (size_t)txs * (CC * HH));
        txs = (txs + 1 == LL) ? 0 : txs + 1;

        // 10. lgkm-only drain + raw barrier (out stores/x loads stay in flight)
        asm volatile("s_waitcnt lgkmcnt(0)" ::: "memory");
        __builtin_amdgcn_s_barrier();
        __builtin_amdgcn_sched_barrier(0);
        asm volatile("" ::: "memory");
    }
}

extern "C" void kernel_launch(void* const* d_in, const int* in_sizes, int n_in,
                              void* d_out, int out_size, void* d_ws, size_t ws_size,
                              hipStream_t stream) {
    const float* seqs  = (const float*)d_in[0];
    const unsigned char* tmask = (const unsigned char*)d_in[1];
    // d_in[2] = attention_mask (all false, unused)
    const float* W_ih  = (const float*)d_in[3];
    const float* W_hh  = (const float*)d_in[4];
    const float* b_ih  = (const float*)d_in[5];
    const float* b_hh  = (const float*)d_in[6];
    float* out = (float*)d_out;

    char* ws = (char*)d_ws;
    int*   lens   = (int*)(ws);                       // 1 KB
    short* wih_hi = (short*)(ws + 1024);              // 384 KB
    short* whh_hi = (short*)(ws + 1024 + 393216);     // 384 KB

    compute_lens_kernel<<<1, BB, 0, stream>>>(tmask, lens);
    wsplit_kernel<<<768, 256, 0, stream>>>(W_ih, W_hh, wih_hi, whh_hi);

    gru_fused_kernel<<<dim3(32, CC), 512, 0, stream>>>(
        seqs, lens, wih_hi, whh_hi, b_ih, b_hh, out);
}